// Round 2
// baseline (956.069 us; speedup 1.0000x reference)
//
#include <hip/hip_runtime.h>

// GroupedLinear: out[T,OUT] = x[T,IN] @ W[e]^T + bias[e], expert-ranged rows.
// E=8, IN=OUT=2048, T=16384. fp32 in/out, bf16 MFMA compute.
//
// Round 2: conservative correctness-first variant of the m90/m92-shaped
// kernel. 128x128 block tile, 4 waves @ 64x64, 4x4 grid of
// v_mfma_f32_16x16x32_bf16, BK=64, single LDS buffer, NO software
// pipeline, scalar RNE fp32->bf16 staging (no perm-pack, no type-punned
// vector LDS stores).

typedef __attribute__((ext_vector_type(8))) short short8;
typedef __attribute__((ext_vector_type(4))) float f32x4;

#define LDT 72  // LDS row stride in bf16 elems: 64 + 8 pad

// round-to-nearest-even fp32 -> bf16 (inputs are finite; no NaN handling)
__device__ __forceinline__ unsigned short f2bf(float f) {
    unsigned u = __builtin_bit_cast(unsigned, f);
    u += 0x7FFFu + ((u >> 16) & 1u);
    return (unsigned short)(u >> 16);
}

__global__ __launch_bounds__(256, 2)
void grouped_gemm_kernel(const float* __restrict__ x,
                         const float* __restrict__ w,
                         const float* __restrict__ bias,
                         const int* __restrict__ tpe,
                         float* __restrict__ out)
{
    __shared__ __align__(16) unsigned short As[128 * LDT];
    __shared__ __align__(16) unsigned short Bs[128 * LDT];

    const int e = blockIdx.z;
    int off = 0, cnt = 0;
#pragma unroll
    for (int i = 0; i < 8; ++i) {
        int c = tpe[i];
        if (i < e) off += c;
        if (i == e) cnt = c;
    }
    const int m0 = blockIdx.y * 128;
    if (m0 >= cnt) return;               // no tokens for this tile
    const int rows = min(128, cnt - m0); // valid rows in this tile
    const int row0 = off + m0;           // first global token row
    const int n0 = blockIdx.x * 128;     // output-column tile

    const int tid = threadIdx.x;
    // Staging: 256 threads = 16 rows x 16 float4-cols per pass; 8 passes
    // cover 128 rows x 64 cols (one BK=64 K-slab of A and B tiles).
    const int sr = tid >> 4;        // 0..15
    const int sc = (tid & 15) * 4;  // 0,4,...,60

    const float* gA = x + (size_t)row0 * 2048 + sc;
    const float* gB = w + (size_t)e * 4194304 + (size_t)(n0 + sr) * 2048 + sc;

    // A row byte offsets per pass, clamped (out-of-range rows re-read the
    // last valid token; their products feed only unstored output rows).
    int arow[8];
#pragma unroll
    for (int p = 0; p < 8; ++p) {
        int r = sr + p * 16;
        arow[p] = ((r < rows) ? r : (rows - 1)) * 2048;
    }

    // Wave / fragment coords (16x16x32 MFMA):
    //   A frag: m = lane&15, k = (lane>>4)*8 + j      (j = 0..7 contiguous)
    //   B frag: n = lane&15, k = (lane>>4)*8 + j
    //   D frag: col = lane&15, row = (lane>>4)*4 + reg
    const int lane = tid & 63;
    const int wid  = tid >> 6;        // 0..3
    const int wm   = (wid & 1) * 64;  // wave M origin in tile
    const int wn   = (wid >> 1) * 64; // wave N origin in tile
    const int fr   = lane & 15;
    const int fq   = lane >> 4;

    f32x4 acc[4][4];
#pragma unroll
    for (int i = 0; i < 4; ++i)
#pragma unroll
        for (int j = 0; j < 4; ++j)
            acc[i][j] = (f32x4){0.f, 0.f, 0.f, 0.f};

    for (int kt = 0; kt < 32; ++kt) {
        const int kk = kt * 64;
        __syncthreads();  // previous tile fully consumed
#pragma unroll
        for (int p = 0; p < 8; ++p) {
            f32x4 a = *(const f32x4*)(gA + arow[p] + kk);
            f32x4 b = *(const f32x4*)(gB + p * 32768 + kk);
            const int rbase = (sr + p * 16) * LDT + sc;
            As[rbase + 0] = f2bf(a.x);
            As[rbase + 1] = f2bf(a.y);
            As[rbase + 2] = f2bf(a.z);
            As[rbase + 3] = f2bf(a.w);
            Bs[rbase + 0] = f2bf(b.x);
            Bs[rbase + 1] = f2bf(b.y);
            Bs[rbase + 2] = f2bf(b.z);
            Bs[rbase + 3] = f2bf(b.w);
        }
        __syncthreads();  // tile ready

#pragma unroll
        for (int ks = 0; ks < 2; ++ks) {
            short8 af[4], bf[4];
#pragma unroll
            for (int i = 0; i < 4; ++i)
                af[i] = *(const short8*)(As + (wm + i * 16 + fr) * LDT + ks * 32 + fq * 8);
#pragma unroll
            for (int j = 0; j < 4; ++j)
                bf[j] = *(const short8*)(Bs + (wn + j * 16 + fr) * LDT + ks * 32 + fq * 8);
#pragma unroll
            for (int i = 0; i < 4; ++i)
#pragma unroll
                for (int j = 0; j < 4; ++j)
                    acc[i][j] = __builtin_amdgcn_mfma_f32_16x16x32_bf16(af[i], bf[j], acc[i][j], 0, 0, 0);
        }
    }

    // Epilogue: D row = wm + i*16 + fq*4 + r (M), col = n0 + wn + j*16 + fr (N)
#pragma unroll
    for (int j = 0; j < 4; ++j) {
        const int col = n0 + wn + j * 16 + fr;
        const float bv = bias[e * 2048 + col];
#pragma unroll
        for (int i = 0; i < 4; ++i) {
            const int rbase = wm + i * 16 + fq * 4;
#pragma unroll
            for (int r = 0; r < 4; ++r) {
                const int lr = rbase + r;
                if (lr < rows)
                    out[(size_t)(row0 + lr) * 2048 + col] = acc[i][j][r] + bv;
            }
        }
    }
}

extern "C" void kernel_launch(void* const* d_in, const int* in_sizes, int n_in,
                              void* d_out, int out_size, void* d_ws, size_t ws_size,
                              hipStream_t stream) {
    const float* x    = (const float*)d_in[0];
    const float* w    = (const float*)d_in[1];
    const float* bias = (const float*)d_in[2];
    const int*   tpe  = (const int*)d_in[3];
    float* out = (float*)d_out;

    // grid: n-tiles (2048/128=16), m-tiles (cap 2304/128=18), experts (8)
    dim3 grid(16, 18, 8);
    grouped_gemm_kernel<<<grid, 256, 0, stream>>>(x, w, bias, tpe, out);
}